// Round 6
// baseline (4195.624 us; speedup 1.0000x reference)
//
#include <hip/hip_runtime.h>

#define Bn   128
#define Tn   512
#define Kn   12
#define Hn   256
#define NWG  256
#define ARR      32768            // 128*256 elements per state array
#define SSTRIDE  (4*ARR)          // ushorts per state buffer (h_hi,h_lo,c_hi,c_lo)
#define CTRL_BYTES 6144           // slots[256]@0, xcd_cnt[32]@1024, flag[(x*4+g)]@2048+idx*128
#define HWREG_XCC_ID 63508        // hwreg(HW_REG_XCC_ID=20, offset 0, size 32)

typedef __attribute__((ext_vector_type(8))) short bf16x8;
typedef __attribute__((ext_vector_type(4))) float f32x4;

__device__ inline unsigned short f2bf(float x) {
  union { float f; unsigned u; } v; v.f = x;
  unsigned r = v.u + 0x7fffu + ((v.u >> 16) & 1u);
  return (unsigned short)(r >> 16);
}
__device__ inline float bf2f(unsigned short h) {
  union { unsigned u; float f; } v; v.u = ((unsigned)h) << 16;
  return v.f;
}
__device__ inline float sigmf(float x) { return 1.0f / (1.0f + __expf(-x)); }

// ROUND-20: R13 PROVEN KERNEL (verbatim data path + sync protocol) with the
// output GEMV fused into the final step.
// R15-R19 post-mortem: the XCD-local 8x16 restructure fails with a
// BIT-IDENTICAL absmax (0.1767578125) under FOUR different sync mechanisms,
// including R19's isolation run using this kernel's proven MALL protocol
// verbatim -> the restructured data flow itself deterministically computes
// wrong values (bug unfound after nine audits); branch abandoned per the
// isolation contract. This round re-anchors on R13 and removes the separate
// out_gemv dispatch: at t=511 each owner already holds its batch's exact
// fp32 h values in registers, so it accumulates sum(h*lw) locally and does
// ONE device-scope atomicAdd per (owner,batch) into out (harness zeroes out
// before launch; atomicAdd on global is device-scope on gfx950). Recurrence
// numerics bit-identical to R13; only the final dot's summation order
// changes (absmax ~1e-7 << 3.5e-3 threshold).
// Architecture (R13): 256 WGs (1/CU, cooperative), WG=(bg: 32 batches)x(4
// j-cols). wave0: 16 gate cols (A=h); waves1-3: 48 decomp cols (A=c).
// Split-bf16 (hi+lo, 3 MFMA) keeps recurrence numerics exact to output
// rounding; owner threads keep exact fp32 c in registers across all 512
// steps. State double-buffered in d_ws; owners publish via packed 8B
// agent-scope (sc1) write-through atomic stores. Per-step sync: wave0-only
// vmcnt drain -> per-WG slot store -> per-(XCD,group) leader polls its
// group's 64 slots -> ONE acquire fence (L2 inv) per XCD per group ->
// 128B-isolated flag -> consumers single-lane poll.
__global__ void __launch_bounds__(256, 1) mtlstm_kernel(
    const float* __restrict__ xd, const float* __restrict__ dtp,
    const float* __restrict__ wih, const float* __restrict__ whh,
    const float* __restrict__ bias, const float* __restrict__ wdc,
    const float* __restrict__ bdc, const float* __restrict__ lw,
    const float* __restrict__ lb, float* __restrict__ out,
    unsigned char* __restrict__ ws)
{
  __shared__ __align__(16) float xs_lds[32 * Kn];
  __shared__ __align__(16) float dt_lds[32 * Kn];
  __shared__ float g_lds[32 * 16];      // activated gates [b_local][jj*4+g]
  __shared__ float dsum_lds[32 * 48];   // decomp contribs [b_local][jj][k]
  __shared__ unsigned ld_info[2];       // [0]=is_leader, [1]=flag index

  unsigned* slots    = (unsigned*)ws;                 // [256], monotone gens
  unsigned* xcd_cnt  = (unsigned*)(ws + 1024);        // [32] rank counters (xcd*4+bg)
  unsigned* flags    = (unsigned*)(ws + 2048);        // flag[idx] at +idx*32 u32 (128B apart)
  unsigned short* state = (unsigned short*)(ws + CTRL_BYTES);

  const int tid = threadIdx.x;
  const int wv  = tid >> 6;        // wave 0: gates(h); waves 1..3: decomp(c)
  const int l   = tid & 63;
  const int n   = l & 15;          // MFMA col / A-row within tile
  const int oct = l >> 4;          // k-octet

  const int wgid = blockIdx.x;
  const int bg = wgid >> 6;        // batch group 0..3 (32 b each)
  const int j0 = (wgid & 63) * 4;  // 4 j-columns per WG

  // ---- one-time: leader election, one per (XCD, group) pair ----
  if (tid == 0) {
    unsigned xcd = __builtin_amdgcn_s_getreg(HWREG_XCC_ID) & 7u;
    unsigned idx = xcd * 4u + (unsigned)bg;
    unsigned r = __hip_atomic_fetch_add(xcd_cnt + idx, 1u, __ATOMIC_RELAXED,
                                        __HIP_MEMORY_SCOPE_AGENT);
    ld_info[0] = (r == 0u);
    ld_info[1] = idx;
  }

  // ---- one-time weight setup: per-lane 16 cols x 256 k, split hi/lo bf16 ----
  const float* rowp;
  float biasv;
  int kd = 0, jjd = 0;
  float wx[12];
  if (wv == 0) {
    int jj = n >> 2, g = n & 3;
    int grow = g * Hn + j0 + jj;
    rowp = whh + (size_t)grow * Hn;
    biasv = bias[grow];
#pragma unroll
    for (int kk = 0; kk < 12; ++kk) wx[kk] = wih[grow * 12 + kk];
  } else {
    int q = (wv - 1) * 16 + n;     // 0..47
    int jj = q / 12;
    int k  = q - jj * 12;
    kd = k; jjd = jj;
    rowp = wdc + ((size_t)k * Hn + (j0 + jj)) * Hn;
    biasv = bdc[k * Hn + j0 + jj];
#pragma unroll
    for (int kk = 0; kk < 12; ++kk) wx[kk] = 0.f;
  }

  bf16x8 wh[8], wl[8];
#pragma unroll
  for (int ks = 0; ks < 8; ++ks) {
    const float* p = rowp + ks * 32 + oct * 8;
#pragma unroll
    for (int e = 0; e < 8; ++e) {
      float x = p[e];
      unsigned short hi = f2bf(x);
      unsigned short lo = f2bf(x - bf2f(hi));
      wh[ks][e] = (short)hi;
      wl[ks][e] = (short)lo;
    }
  }

  const int aoff0 = (bg * 32 + n) * Hn + oct * 8;  // M-tile 0 A offset
  const int aoff1 = aoff0 + 16 * Hn;               // M-tile 1
  const int hsel  = (wv == 0) ? 0 : 2 * ARR;       // h arrays vs c arrays

  float c_reg[4] = {0.f, 0.f, 0.f, 0.f};  // exact fp32 c, owners tid<32 (4 j each)
  unsigned gen = 0;

  // ---- prologue: stage x_0, dt_0 ----
  if (tid < 96) {
    int bl = tid / 3, ch = tid % 3;
    float4 v = *(const float4*)(xd + ((size_t)(bg * 32 + bl) * Tn + 0) * Kn + ch * 4);
    *(float4*)(&xs_lds[bl * 12 + ch * 4]) = v;
  } else if (tid < 192) {
    int q2 = tid - 96;
    int bl = q2 / 3, ch = q2 % 3;
    float4 v = *(const float4*)(dtp + ((size_t)(bg * 32 + bl) * Tn + 0) * Kn + ch * 4);
    *(float4*)(&dt_lds[bl * 12 + ch * 4]) = v;
  }
  __syncthreads();
  const bool leader = ld_info[0] != 0u;
  unsigned* myflag = flags + ld_info[1] * 32;
  unsigned* gslot = slots + bg * 64;     // this group's 64 slots (2 lines)

  for (int t = 0; t < Tn; ++t) {
    const unsigned short* sb = state + (t & 1) * SSTRIDE + hsel;

    // ---- GEMM: 2 M-tiles x 1 N-tile, K=256, split-bf16 (3 MFMA) ----
    f32x4 acc0 = {0.f, 0.f, 0.f, 0.f};
    f32x4 acc1 = {0.f, 0.f, 0.f, 0.f};
#pragma unroll
    for (int ks = 0; ks < 8; ++ks) {
      int o = ks * 32;
      bf16x8 a0h = *(const bf16x8*)(sb + aoff0 + o);
      bf16x8 a1h = *(const bf16x8*)(sb + aoff1 + o);
      bf16x8 a0l = *(const bf16x8*)(sb + ARR + aoff0 + o);
      bf16x8 a1l = *(const bf16x8*)(sb + ARR + aoff1 + o);
      acc0 = __builtin_amdgcn_mfma_f32_16x16x32_bf16(a0h, wh[ks], acc0, 0, 0, 0);
      acc1 = __builtin_amdgcn_mfma_f32_16x16x32_bf16(a1h, wh[ks], acc1, 0, 0, 0);
      acc0 = __builtin_amdgcn_mfma_f32_16x16x32_bf16(a0h, wl[ks], acc0, 0, 0, 0);
      acc1 = __builtin_amdgcn_mfma_f32_16x16x32_bf16(a1h, wl[ks], acc1, 0, 0, 0);
      acc0 = __builtin_amdgcn_mfma_f32_16x16x32_bf16(a0l, wh[ks], acc0, 0, 0, 0);
      acc1 = __builtin_amdgcn_mfma_f32_16x16x32_bf16(a1l, wh[ks], acc1, 0, 0, 0);
    }

    // ---- epilogue: D layout row=(oct*4+r) (=b_local within tile), col=n ----
    // (x@W_ih stays HERE: it executes under the MFMA-result waitcnt shadow)
    if (wv == 0) {
      int g = n & 3;
#pragma unroll
      for (int mt = 0; mt < 2; ++mt) {
        f32x4 a = mt ? acc1 : acc0;
#pragma unroll
        for (int r = 0; r < 4; ++r) {
          int bl = mt * 16 + oct * 4 + r;
          float xwv = 0.f;
#pragma unroll
          for (int kk = 0; kk < 12; ++kk) xwv += xs_lds[bl * 12 + kk] * wx[kk];
          float v = a[r] + biasv + xwv;
          float act = (g == 2) ? tanhf(v) : sigmf(v);
          g_lds[bl * 16 + n] = act;
        }
      }
    } else {
#pragma unroll
      for (int mt = 0; mt < 2; ++mt) {
        f32x4 a = mt ? acc1 : acc0;
#pragma unroll
        for (int r = 0; r < 4; ++r) {
          int bl = mt * 16 + oct * 4 + r;
          float v = a[r] + biasv;
          float cs = tanhf(v);
          float dtv = dt_lds[bl * 12 + kd];
          float coef = 1.0f / __logf(2.718281828459045f + dtv) - 1.0f;
          dsum_lds[bl * 48 + jjd * 12 + kd] = cs * coef;
        }
      }
    }
    __syncthreads();   // C: g_lds/dsum_lds ready for owner; xs(t) reads done

    ++gen;
    if (wv == 0) {
      // ---- owner update (tid<32) + packed 8B sc1 stores ----
      if (tid < 32) {
        int b = tid;
        union P { unsigned short u[4]; unsigned long long q; } ph, pl, pc, pq;
        float pacc = 0.f;           // fused output: sum_j h*lw (last step only)
#pragma unroll
        for (int jj = 0; jj < 4; ++jj) {
          float iv = g_lds[b * 16 + jj * 4 + 0];
          float fv = g_lds[b * 16 + jj * 4 + 1];
          float gv = g_lds[b * 16 + jj * 4 + 2];
          float ov = g_lds[b * 16 + jj * 4 + 3];
          float S = 0.f;
#pragma unroll
          for (int k = 0; k < 12; ++k) S += dsum_lds[b * 48 + jj * 12 + k];
          float cst = c_reg[jj] + S;
          float cn = fv * cst + iv * gv;
          float hn = ov * tanhf(cn);
          c_reg[jj] = cn;
          ph.u[jj] = f2bf(hn);
          pl.u[jj] = f2bf(hn - bf2f(ph.u[jj]));
          pc.u[jj] = f2bf(cn);
          pq.u[jj] = f2bf(cn - bf2f(pc.u[jj]));
          if (t == Tn - 1)
            pacc += hn * lw[j0 + jj];
        }
        unsigned long long* db = (unsigned long long*)state
            + (size_t)((t + 1) & 1) * (SSTRIDE / 4)
            + (size_t)(bg * 32 + b) * 64 + (j0 >> 2);
        __hip_atomic_store(db + 0 * (ARR / 4), ph.q, __ATOMIC_RELAXED, __HIP_MEMORY_SCOPE_AGENT);
        __hip_atomic_store(db + 1 * (ARR / 4), pl.q, __ATOMIC_RELAXED, __HIP_MEMORY_SCOPE_AGENT);
        __hip_atomic_store(db + 2 * (ARR / 4), pc.q, __ATOMIC_RELAXED, __HIP_MEMORY_SCOPE_AGENT);
        __hip_atomic_store(db + 3 * (ARR / 4), pq.q, __ATOMIC_RELAXED, __HIP_MEMORY_SCOPE_AGENT);
        if (t == Tn - 1) {
          // device-scope atomic accumulate of this WG's 4-column partial dot;
          // the j0==0 WG of each group contributes the bias exactly once.
          float vout = pacc + (j0 == 0 ? lb[0] : 0.f);
          atomicAdd(out + (bg * 32 + b), vout);
        }
      }
      // wave-0-only drain: owner stores ack'd at MALL before slot store
      asm volatile("s_waitcnt vmcnt(0)" ::: "memory");
      if (tid == 0)
        __hip_atomic_store(slots + wgid, gen, __ATOMIC_RELAXED,
                           __HIP_MEMORY_SCOPE_AGENT);
      if (leader) {
        // poll THIS GROUP's 64 slots (1 load/lane) — r10 position & semantics
        for (;;) {
          unsigned v = __hip_atomic_load(gslot + l, __ATOMIC_RELAXED,
                                         __HIP_MEMORY_SCOPE_AGENT);
          if (__all((int)(v >= gen))) break;
          __builtin_amdgcn_s_sleep(1);
        }
        __builtin_amdgcn_fence(__ATOMIC_ACQUIRE, "agent");  // inv my XCD's L2
        if (tid == 0)
          __hip_atomic_store(myflag, gen, __ATOMIC_RELAXED, __HIP_MEMORY_SCOPE_AGENT);
      } else {
        // single-lane flag poll: flag==gen => group state at MALL + my L2 inv'd
        for (;;) {
          unsigned v = gen;
          if (l == 0)
            v = __hip_atomic_load(myflag, __ATOMIC_RELAXED, __HIP_MEMORY_SCOPE_AGENT);
          if (__all((int)(v >= gen))) break;
          __builtin_amdgcn_s_sleep(1);
        }
      }
    } else if (t + 1 < Tn) {
      // ---- waves 1-3: stage x_{t+1}, dt_{t+1} during the barrier window ----
      int q = tid - 64;            // 0..191
      if (q < 96) {
        int bl = q / 3, ch = q % 3;
        float4 v = *(const float4*)(xd + ((size_t)(bg * 32 + bl) * Tn + (t + 1)) * Kn + ch * 4);
        *(float4*)(&xs_lds[bl * 12 + ch * 4]) = v;
      } else {
        int q2 = q - 96;
        int bl = q2 / 3, ch = q2 % 3;
        float4 v = *(const float4*)(dtp + ((size_t)(bg * 32 + bl) * Tn + (t + 1)) * Kn + ch * 4);
        *(float4*)(&dt_lds[bl * 12 + ch * 4]) = v;
      }
    }
    __syncthreads();   // D: barrier passed + x/dt(t+1) staged
  }
}

extern "C" void kernel_launch(void* const* d_in, const int* in_sizes, int n_in,
                              void* d_out, int out_size, void* d_ws, size_t ws_size,
                              hipStream_t stream)
{
  const float* xd   = (const float*)d_in[0];
  const float* dtp  = (const float*)d_in[1];
  const float* wih  = (const float*)d_in[2];
  const float* whh  = (const float*)d_in[3];
  const float* bias = (const float*)d_in[4];
  const float* wdc  = (const float*)d_in[5];
  const float* bdc  = (const float*)d_in[6];
  const float* lw   = (const float*)d_in[7];
  const float* lb   = (const float*)d_in[8];
  float* out = (float*)d_out;
  unsigned char* ws = (unsigned char*)d_ws;

  // zero slots + counters/flags + both state buffers (ws poisoned 0xAA)
  hipMemsetAsync(ws, 0, CTRL_BYTES + 2 * SSTRIDE * 2, stream);

  void* args[] = { (void*)&xd, (void*)&dtp, (void*)&wih, (void*)&whh,
                   (void*)&bias, (void*)&wdc, (void*)&bdc, (void*)&lw,
                   (void*)&lb, (void*)&out, (void*)&ws };
  hipLaunchCooperativeKernel((const void*)mtlstm_kernel, dim3(NWG), dim3(256),
                             args, 0, stream);
}

// Round 7
// 3801.674 us; speedup vs baseline: 1.1036x; 1.1036x over previous
//
#include <hip/hip_runtime.h>

#define Bn   128
#define Tn   512
#define Kn   12
#define Hn   256
#define NWG  256
#define ARR      32768            // 128*256 elements per state array
#define SSTRIDE  (4*ARR)          // ushorts per state buffer (h_hi,h_lo,c_hi,c_lo)
#define CTRL_BYTES 40960          // slots[256] @ stride 128B (32KB); xcd_cnt[32]@32768; flags@34816 stride 128B
#define HWREG_XCC_ID 63508        // hwreg(HW_REG_XCC_ID=20, offset 0, size 32)

typedef __attribute__((ext_vector_type(8))) short bf16x8;
typedef __attribute__((ext_vector_type(4))) float f32x4;

__device__ inline unsigned short f2bf(float x) {
  union { float f; unsigned u; } v; v.f = x;
  unsigned r = v.u + 0x7fffu + ((v.u >> 16) & 1u);
  return (unsigned short)(r >> 16);
}
__device__ inline float bf2f(unsigned short h) {
  union { unsigned u; float f; } v; v.u = ((unsigned)h) << 16;
  return v.f;
}
__device__ inline float sigmf(float x) { return 1.0f / (1.0f + __expf(-x)); }

// ROUND-21: R20 (passing, fused GEMV) + slot-line de-serialization.
// R20 re-anchored at 4195us/absmax 0.0. Counters: MfmaUtil 4%, VALUBusy 9%,
// HBM 3.3% -> still sync-latency-bound at 8.1us/step. Chain arithmetic says
// ~5 MALL RTTs ~= 9-12k cy; the residual ~7k cy of the 19.5k-cy step is
// serialization: all 256 slot words were packed in 1KB, so each group's 64
// slot stores hit TWO 128B lines -> 64 near-simultaneous agent write-
// throughs from 64 CUs serialize at one MALL slice (~2-4k cy for the LAST
// slot, which gates the leader), and 32 leaders x 64 lanes re-poll the same
// two lines every RTT. This round:
//  (1) one slot per 128B line (32KB region): stores ack in parallel slices,
//      leader poll fans out across 64 lines in parallel;
//  (2) laggard-predicated leader poll: lanes latch slots already >= gen and
//      stop re-loading them (monotone slots make the latch sound).
// Data path, owner math, leader/fence/flag protocol: verbatim R20.
// Architecture (R13): 256 WGs (1/CU, cooperative), WG=(bg: 32 batches)x(4
// j-cols). wave0: 16 gate cols (A=h); waves1-3: 48 decomp cols (A=c).
// Split-bf16 (hi+lo, 3 MFMA); owner threads keep exact fp32 c in registers
// across all 512 steps; state double-buffered in d_ws; owners publish via
// packed 8B agent-scope write-through atomic stores. Per-step sync: wave0
// vmcnt drain -> per-WG slot store -> per-(XCD,group) leader polls its
// group's 64 slots -> ONE acquire fence (L2 inv) per XCD per group ->
// 128B-isolated flag -> consumers single-lane poll. Output GEMV fused into
// t=511 (one device-scope atomicAdd per (owner,batch)).
__global__ void __launch_bounds__(256, 1) mtlstm_kernel(
    const float* __restrict__ xd, const float* __restrict__ dtp,
    const float* __restrict__ wih, const float* __restrict__ whh,
    const float* __restrict__ bias, const float* __restrict__ wdc,
    const float* __restrict__ bdc, const float* __restrict__ lw,
    const float* __restrict__ lb, float* __restrict__ out,
    unsigned char* __restrict__ ws)
{
  __shared__ __align__(16) float xs_lds[32 * Kn];
  __shared__ __align__(16) float dt_lds[32 * Kn];
  __shared__ float g_lds[32 * 16];      // activated gates [b_local][jj*4+g]
  __shared__ float dsum_lds[32 * 48];   // decomp contribs [b_local][jj][k]
  __shared__ unsigned ld_info[2];       // [0]=is_leader, [1]=flag index

  // slot i lives at ws + i*128 (one 128B line per slot)
  unsigned* xcd_cnt  = (unsigned*)(ws + 32768);       // [32] rank counters (xcd*4+bg)
  unsigned char* flags_base = ws + 34816;             // flag idx at +idx*128
  unsigned short* state = (unsigned short*)(ws + CTRL_BYTES);

  const int tid = threadIdx.x;
  const int wv  = tid >> 6;        // wave 0: gates(h); waves 1..3: decomp(c)
  const int l   = tid & 63;
  const int n   = l & 15;          // MFMA col / A-row within tile
  const int oct = l >> 4;          // k-octet

  const int wgid = blockIdx.x;
  const int bg = wgid >> 6;        // batch group 0..3 (32 b each)
  const int j0 = (wgid & 63) * 4;  // 4 j-columns per WG

  // ---- one-time: leader election, one per (XCD, group) pair ----
  if (tid == 0) {
    unsigned xcd = __builtin_amdgcn_s_getreg(HWREG_XCC_ID) & 7u;
    unsigned idx = xcd * 4u + (unsigned)bg;
    unsigned r = __hip_atomic_fetch_add(xcd_cnt + idx, 1u, __ATOMIC_RELAXED,
                                        __HIP_MEMORY_SCOPE_AGENT);
    ld_info[0] = (r == 0u);
    ld_info[1] = idx;
  }

  // ---- one-time weight setup: per-lane 16 cols x 256 k, split hi/lo bf16 ----
  const float* rowp;
  float biasv;
  int kd = 0, jjd = 0;
  float wx[12];
  if (wv == 0) {
    int jj = n >> 2, g = n & 3;
    int grow = g * Hn + j0 + jj;
    rowp = whh + (size_t)grow * Hn;
    biasv = bias[grow];
#pragma unroll
    for (int kk = 0; kk < 12; ++kk) wx[kk] = wih[grow * 12 + kk];
  } else {
    int q = (wv - 1) * 16 + n;     // 0..47
    int jj = q / 12;
    int k  = q - jj * 12;
    kd = k; jjd = jj;
    rowp = wdc + ((size_t)k * Hn + (j0 + jj)) * Hn;
    biasv = bdc[k * Hn + j0 + jj];
#pragma unroll
    for (int kk = 0; kk < 12; ++kk) wx[kk] = 0.f;
  }

  bf16x8 wh[8], wl[8];
#pragma unroll
  for (int ks = 0; ks < 8; ++ks) {
    const float* p = rowp + ks * 32 + oct * 8;
#pragma unroll
    for (int e = 0; e < 8; ++e) {
      float x = p[e];
      unsigned short hi = f2bf(x);
      unsigned short lo = f2bf(x - bf2f(hi));
      wh[ks][e] = (short)hi;
      wl[ks][e] = (short)lo;
    }
  }

  const int aoff0 = (bg * 32 + n) * Hn + oct * 8;  // M-tile 0 A offset
  const int aoff1 = aoff0 + 16 * Hn;               // M-tile 1
  const int hsel  = (wv == 0) ? 0 : 2 * ARR;       // h arrays vs c arrays

  float c_reg[4] = {0.f, 0.f, 0.f, 0.f};  // exact fp32 c, owners tid<32 (4 j each)
  unsigned gen = 0;

  // ---- prologue: stage x_0, dt_0 ----
  if (tid < 96) {
    int bl = tid / 3, ch = tid % 3;
    float4 v = *(const float4*)(xd + ((size_t)(bg * 32 + bl) * Tn + 0) * Kn + ch * 4);
    *(float4*)(&xs_lds[bl * 12 + ch * 4]) = v;
  } else if (tid < 192) {
    int q2 = tid - 96;
    int bl = q2 / 3, ch = q2 % 3;
    float4 v = *(const float4*)(dtp + ((size_t)(bg * 32 + bl) * Tn + 0) * Kn + ch * 4);
    *(float4*)(&dt_lds[bl * 12 + ch * 4]) = v;
  }
  __syncthreads();
  const bool leader = ld_info[0] != 0u;
  unsigned* myflag  = (unsigned*)(flags_base + (size_t)ld_info[1] * 128);
  unsigned* myslot  = (unsigned*)(ws + (size_t)wgid * 128);
  unsigned* polslot = (unsigned*)(ws + (size_t)(bg * 64 + l) * 128);  // lane's slot

  for (int t = 0; t < Tn; ++t) {
    const unsigned short* sb = state + (t & 1) * SSTRIDE + hsel;

    // ---- GEMM: 2 M-tiles x 1 N-tile, K=256, split-bf16 (3 MFMA) ----
    f32x4 acc0 = {0.f, 0.f, 0.f, 0.f};
    f32x4 acc1 = {0.f, 0.f, 0.f, 0.f};
#pragma unroll
    for (int ks = 0; ks < 8; ++ks) {
      int o = ks * 32;
      bf16x8 a0h = *(const bf16x8*)(sb + aoff0 + o);
      bf16x8 a1h = *(const bf16x8*)(sb + aoff1 + o);
      bf16x8 a0l = *(const bf16x8*)(sb + ARR + aoff0 + o);
      bf16x8 a1l = *(const bf16x8*)(sb + ARR + aoff1 + o);
      acc0 = __builtin_amdgcn_mfma_f32_16x16x32_bf16(a0h, wh[ks], acc0, 0, 0, 0);
      acc1 = __builtin_amdgcn_mfma_f32_16x16x32_bf16(a1h, wh[ks], acc1, 0, 0, 0);
      acc0 = __builtin_amdgcn_mfma_f32_16x16x32_bf16(a0h, wl[ks], acc0, 0, 0, 0);
      acc1 = __builtin_amdgcn_mfma_f32_16x16x32_bf16(a1h, wl[ks], acc1, 0, 0, 0);
      acc0 = __builtin_amdgcn_mfma_f32_16x16x32_bf16(a0l, wh[ks], acc0, 0, 0, 0);
      acc1 = __builtin_amdgcn_mfma_f32_16x16x32_bf16(a1l, wh[ks], acc1, 0, 0, 0);
    }

    // ---- epilogue: D layout row=(oct*4+r) (=b_local within tile), col=n ----
    // (x@W_ih stays HERE: it executes under the MFMA-result waitcnt shadow)
    if (wv == 0) {
      int g = n & 3;
#pragma unroll
      for (int mt = 0; mt < 2; ++mt) {
        f32x4 a = mt ? acc1 : acc0;
#pragma unroll
        for (int r = 0; r < 4; ++r) {
          int bl = mt * 16 + oct * 4 + r;
          float xwv = 0.f;
#pragma unroll
          for (int kk = 0; kk < 12; ++kk) xwv += xs_lds[bl * 12 + kk] * wx[kk];
          float v = a[r] + biasv + xwv;
          float act = (g == 2) ? tanhf(v) : sigmf(v);
          g_lds[bl * 16 + n] = act;
        }
      }
    } else {
#pragma unroll
      for (int mt = 0; mt < 2; ++mt) {
        f32x4 a = mt ? acc1 : acc0;
#pragma unroll
        for (int r = 0; r < 4; ++r) {
          int bl = mt * 16 + oct * 4 + r;
          float v = a[r] + biasv;
          float cs = tanhf(v);
          float dtv = dt_lds[bl * 12 + kd];
          float coef = 1.0f / __logf(2.718281828459045f + dtv) - 1.0f;
          dsum_lds[bl * 48 + jjd * 12 + kd] = cs * coef;
        }
      }
    }
    __syncthreads();   // C: g_lds/dsum_lds ready for owner; xs(t) reads done

    ++gen;
    if (wv == 0) {
      // ---- owner update (tid<32) + packed 8B sc1 stores ----
      if (tid < 32) {
        int b = tid;
        union P { unsigned short u[4]; unsigned long long q; } ph, pl, pc, pq;
        float pacc = 0.f;           // fused output: sum_j h*lw (last step only)
#pragma unroll
        for (int jj = 0; jj < 4; ++jj) {
          float iv = g_lds[b * 16 + jj * 4 + 0];
          float fv = g_lds[b * 16 + jj * 4 + 1];
          float gv = g_lds[b * 16 + jj * 4 + 2];
          float ov = g_lds[b * 16 + jj * 4 + 3];
          float S = 0.f;
#pragma unroll
          for (int k = 0; k < 12; ++k) S += dsum_lds[b * 48 + jj * 12 + k];
          float cst = c_reg[jj] + S;
          float cn = fv * cst + iv * gv;
          float hn = ov * tanhf(cn);
          c_reg[jj] = cn;
          ph.u[jj] = f2bf(hn);
          pl.u[jj] = f2bf(hn - bf2f(ph.u[jj]));
          pc.u[jj] = f2bf(cn);
          pq.u[jj] = f2bf(cn - bf2f(pc.u[jj]));
          if (t == Tn - 1)
            pacc += hn * lw[j0 + jj];
        }
        unsigned long long* db = (unsigned long long*)state
            + (size_t)((t + 1) & 1) * (SSTRIDE / 4)
            + (size_t)(bg * 32 + b) * 64 + (j0 >> 2);
        __hip_atomic_store(db + 0 * (ARR / 4), ph.q, __ATOMIC_RELAXED, __HIP_MEMORY_SCOPE_AGENT);
        __hip_atomic_store(db + 1 * (ARR / 4), pl.q, __ATOMIC_RELAXED, __HIP_MEMORY_SCOPE_AGENT);
        __hip_atomic_store(db + 2 * (ARR / 4), pc.q, __ATOMIC_RELAXED, __HIP_MEMORY_SCOPE_AGENT);
        __hip_atomic_store(db + 3 * (ARR / 4), pq.q, __ATOMIC_RELAXED, __HIP_MEMORY_SCOPE_AGENT);
        if (t == Tn - 1) {
          // device-scope atomic accumulate of this WG's 4-column partial dot;
          // the j0==0 WG of each group contributes the bias exactly once.
          float vout = pacc + (j0 == 0 ? lb[0] : 0.f);
          atomicAdd(out + (bg * 32 + b), vout);
        }
      }
      // wave-0-only drain: owner stores ack'd at MALL before slot store
      asm volatile("s_waitcnt vmcnt(0)" ::: "memory");
      if (tid == 0)
        __hip_atomic_store(myslot, gen, __ATOMIC_RELAXED,
                           __HIP_MEMORY_SCOPE_AGENT);
      if (leader) {
        // poll THIS GROUP's 64 slots, one 128B line per lane, laggard-latched
        unsigned vseen = 0;
        for (;;) {
          if (vseen < gen)
            vseen = __hip_atomic_load(polslot, __ATOMIC_RELAXED,
                                      __HIP_MEMORY_SCOPE_AGENT);
          if (__all((int)(vseen >= gen))) break;
          __builtin_amdgcn_s_sleep(1);
        }
        __builtin_amdgcn_fence(__ATOMIC_ACQUIRE, "agent");  // inv my XCD's L2
        if (tid == 0)
          __hip_atomic_store(myflag, gen, __ATOMIC_RELAXED, __HIP_MEMORY_SCOPE_AGENT);
      } else {
        // single-lane flag poll: flag==gen => group state at MALL + my L2 inv'd
        for (;;) {
          unsigned v = gen;
          if (l == 0)
            v = __hip_atomic_load(myflag, __ATOMIC_RELAXED, __HIP_MEMORY_SCOPE_AGENT);
          if (__all((int)(v >= gen))) break;
          __builtin_amdgcn_s_sleep(1);
        }
      }
    } else if (t + 1 < Tn) {
      // ---- waves 1-3: stage x_{t+1}, dt_{t+1} during the barrier window ----
      int q = tid - 64;            // 0..191
      if (q < 96) {
        int bl = q / 3, ch = q % 3;
        float4 v = *(const float4*)(xd + ((size_t)(bg * 32 + bl) * Tn + (t + 1)) * Kn + ch * 4);
        *(float4*)(&xs_lds[bl * 12 + ch * 4]) = v;
      } else {
        int q2 = q - 96;
        int bl = q2 / 3, ch = q2 % 3;
        float4 v = *(const float4*)(dtp + ((size_t)(bg * 32 + bl) * Tn + (t + 1)) * Kn + ch * 4);
        *(float4*)(&dt_lds[bl * 12 + ch * 4]) = v;
      }
    }
    __syncthreads();   // D: barrier passed + x/dt(t+1) staged
  }
}

extern "C" void kernel_launch(void* const* d_in, const int* in_sizes, int n_in,
                              void* d_out, int out_size, void* d_ws, size_t ws_size,
                              hipStream_t stream)
{
  const float* xd   = (const float*)d_in[0];
  const float* dtp  = (const float*)d_in[1];
  const float* wih  = (const float*)d_in[2];
  const float* whh  = (const float*)d_in[3];
  const float* bias = (const float*)d_in[4];
  const float* wdc  = (const float*)d_in[5];
  const float* bdc  = (const float*)d_in[6];
  const float* lw   = (const float*)d_in[7];
  const float* lb   = (const float*)d_in[8];
  float* out = (float*)d_out;
  unsigned char* ws = (unsigned char*)d_ws;

  // zero spread slots + counters/flags + both state buffers
  hipMemsetAsync(ws, 0, CTRL_BYTES + 2 * SSTRIDE * 2, stream);

  void* args[] = { (void*)&xd, (void*)&dtp, (void*)&wih, (void*)&whh,
                   (void*)&bias, (void*)&wdc, (void*)&bdc, (void*)&lw,
                   (void*)&lb, (void*)&out, (void*)&ws };
  hipLaunchCooperativeKernel((const void*)mtlstm_kernel, dim3(NWG), dim3(256),
                             args, 0, stream);
}